// Round 11
// baseline (609.067 us; speedup 1.0000x reference)
//
#include <hip/hip_runtime.h>

// LDPC BP decoder, (3,6)-regular. 1 WG = 1 batch element, 1024 threads.
// Edge e (vn order) = 3v+j; c = e mod 8192; cn-order slot q = 6c+t, e = c+8192t.
//
// r10 lesson: phi primitives MUST be ~correctly-rounded f32 (hw f32 trans
// fail: quantized b=ex-1 at small x flips by log2 per ulp -> absmax 10.5).
// r9 lesson: residual spill (~33MB scratch) = ms[8]+sb bookkeeping pushing
// peak live to ~68 > 64-VGPR budget. This round: fold the sign into the
// stored magnitude (phi(|m|) ^ signbit(m)); pass 2 recomputes mag_sum from
// the 6 signed mags in reference left-fold order and signs via XOR. Peak
// live ~54 < 64. FP chain bit-identical to r9 (absmax 0.25).

constexpr int NUM_VNS  = 16384;
constexpr int NUM_ITER = 8;
constexpr float LLR_MAX  = 20.0f;
constexpr float PHI_MIN  = 8.5e-8f;
constexpr float PHI_MAX  = 16.635532f;

#define THREADS 1024

// exp(x) for x in [0, 16.64]; internal rel err ~2^-42.
__device__ __forceinline__ double lean_exp(double x) {
    double t = x * 1.4426950408889634;
    double k = __builtin_rint(t);
    double r = __builtin_fma(-k, 0.6931471805599453, x);
    r = __builtin_fma(-k, 2.3190468138462996e-17, r);
    double p = 1.0 / 3628800.0;                  // Taylor deg 10, |r|<=0.347
    p = __builtin_fma(p, r, 1.0 / 362880.0);
    p = __builtin_fma(p, r, 1.0 / 40320.0);
    p = __builtin_fma(p, r, 1.0 / 5040.0);
    p = __builtin_fma(p, r, 1.0 / 720.0);
    p = __builtin_fma(p, r, 1.0 / 120.0);
    p = __builtin_fma(p, r, 1.0 / 24.0);
    p = __builtin_fma(p, r, 1.0 / 6.0);
    p = __builtin_fma(p, r, 0.5);
    p = __builtin_fma(p, r, 1.0);
    p = __builtin_fma(p, r, 1.0);
    int ik = (int)k;                              // k in [0,24]
    double s = __hiloint2double((1023 + ik) << 20, 0);
    return p * s;
}

// log(v) for v in [2^-23, 2^25], v an exact f32 value; abs err ~2^-40.
__device__ __forceinline__ double lean_log(double v) {
    int hv = __double2hiint(v);
    int lv = __double2loint(v);
    int e  = (hv >> 20) - 1023;
    double m = __hiloint2double((hv & 0x000FFFFF) | 0x3FF00000, lv);
    if (m >= 1.4142135623730951) { m *= 0.5; e += 1; }   // m in [0.7071,1.4142)
    double t = m - 1.0;
    double d = t + 2.0;
    double r = (double)__builtin_amdgcn_rcpf((float)d);
    r = __builtin_fma(__builtin_fma(-d, r, 1.0), r, r);
    double u = t * r;
    double w = u * u;                             // w <= 0.0295
    double P = 2.0 / 13.0;                        // 2*artanh: deg 6 in w
    P = __builtin_fma(P, w, 2.0 / 11.0);
    P = __builtin_fma(P, w, 2.0 / 9.0);
    P = __builtin_fma(P, w, 2.0 / 7.0);
    P = __builtin_fma(P, w, 2.0 / 5.0);
    P = __builtin_fma(P, w, 2.0 / 3.0);
    P = __builtin_fma(P, w, 2.0);
    double lm = u * P;
    return __builtin_fma((double)e, 0.6931471805599453, lm);
}

__device__ __forceinline__ float phi_f(float xf) {
    xf = fminf(fmaxf(xf, PHI_MIN), PHI_MAX);
    float exf = (float)lean_exp((double)xf);
    float af = exf + 1.0f;
    float bf = exf - 1.0f;
    float la = (float)lean_log((double)af);
    float lb = (float)lean_log((double)bf);
    return la - lb;
}

// phi(|m|) with sign(m<0) folded into the sign bit (sign(0) -> +).
__device__ __forceinline__ float signed_mag(float m) {
    unsigned neg = (m < 0.0f) ? 0x80000000u : 0u;
    float mg = phi_f(fabsf(m));
    return __uint_as_float(__float_as_uint(mg) | neg);
}

__global__ __launch_bounds__(THREADS)
void ldpc_bp_kernel(const float* __restrict__ llr_ch, float* __restrict__ out)
{
    __shared__ float buf[24576];   // 96 KB: msgs/signed-mags t0-2, buf[c+8192t]
    __shared__ float sh32[8192];   // 32 KB: vtot lower, then vtot upper (v-8192)
    __shared__ float W[8192];      // 32 KB: staging window for t3/t4/t5

    const int b   = blockIdx.x;
    const int tid = threadIdx.x;
    const float* __restrict__ llr_b = llr_ch + (size_t)b * NUM_VNS;
    float* __restrict__ out_b = out + (size_t)b * NUM_VNS;

    float msg[3][8];               // t3..t5 messages (signed mags during E)

#pragma unroll
    for (int t = 0; t < 3; ++t)
#pragma unroll
        for (int i = 0; i < 8; ++i) {
            buf[(t << 13) + tid + THREADS * i] = 0.0f;
            msg[t][i] = 0.0f;
        }

    for (int iter = 0; iter <= NUM_ITER; ++iter) {
        const bool last = (iter == NUM_ITER);
        unsigned long long lbase = (unsigned long long)llr_b;
        asm volatile("" : "+s"(lbase));       // LICM fence on llr loads
        const float* lp = (const float*)lbase;

        __syncthreads();                      // prev msg writes -> B reads
        // ---- B: vtot lower, v in [0,8192), from resident buf ----
#pragma unroll
        for (int k = 0; k < 8; ++k) {
            int v = tid + THREADS * k;
            float x = fminf(fmaxf(lp[v], -LLR_MAX), LLR_MAX);
            int e = 3 * v;
            float s = ((buf[e] + buf[e + 1]) + buf[e + 2]) - x;
            if (last) out_b[v] = -s; else sh32[v] = s;
        }
        __syncthreads();

        // ---- E-low (t=0..2, signed mags in place in buf) || stage t3 -> W ----
#pragma unroll
        for (int i = 0; i < 8; ++i) W[tid + THREADS * i] = msg[0][i];
        if (!last) {
#pragma unroll
            for (int i = 0; i < 8; ++i) {
                int c = tid + THREADS * i;
#pragma unroll
                for (int t = 0; t < 3; ++t) {
                    int e = c + (t << 13);
                    int v = (int)(((unsigned)e * 43691u) >> 17);   // e/3
                    float m = sh32[v] - buf[e];
                    buf[e] = signed_mag(m);
                    __builtin_amdgcn_sched_barrier(0);
                }
            }
        }
        __syncthreads();

        // ---- chunk t3: vtot for v in [8192,10922) + thread0: v=10922 ----
#pragma unroll
        for (int k = 0; k < 3; ++k) {
            int r = tid + THREADS * k;
            if (r < 2730) {
                int v = 8192 + r;
                float x = fminf(fmaxf(lp[v], -LLR_MAX), LLR_MAX);
                int j = 3 * r;
                float s = ((W[j] + W[j + 1]) + W[j + 2]) - x;
                if (last) out_b[v] = -s; else sh32[r] = s;
            }
        }
        if (tid == 0) {   // v=10922: edges t3 c8190,c8191 + t4 c0 (own reg)
            float x = fminf(fmaxf(lp[10922], -LLR_MAX), LLR_MAX);
            float s = ((W[8190] + W[8191]) + msg[1][0]) - x;
            if (last) out_b[10922] = -s; else sh32[2730] = s;
        }
        __syncthreads();

        // ---- E-t3 (msg[0] -> signed mags)  ||  stage t4 -> W ----
#pragma unroll
        for (int i = 0; i < 8; ++i) W[tid + THREADS * i] = msg[1][i];
        if (!last) {
#pragma unroll
            for (int i = 0; i < 8; ++i) {
                int e = tid + THREADS * i + 24576;
                int v = (int)(((unsigned)e * 43691u) >> 17);
                float m = sh32[v - 8192] - msg[0][i];
                msg[0][i] = signed_mag(m);
                __builtin_amdgcn_sched_barrier(0);
            }
        }
        __syncthreads();

        // ---- chunk t4: v in [10923,13653) + thread0: v=13653 ----
        {
            float t5c1 = __shfl(msg[2][0], 1);   // t5 c=1 lives in lane 1 (i=0)
#pragma unroll
            for (int k = 0; k < 3; ++k) {
                int r = tid + THREADS * k;
                if (r < 2730) {
                    int v = 10923 + r;
                    float x = fminf(fmaxf(lp[v], -LLR_MAX), LLR_MAX);
                    int j = 3 * r + 1;
                    float s = ((W[j] + W[j + 1]) + W[j + 2]) - x;
                    if (last) out_b[v] = -s; else sh32[2731 + r] = s;
                }
            }
            if (tid == 0) {  // v=13653: t4 c8191 (W) + t5 c0 (own) + t5 c1 (shfl)
                float x = fminf(fmaxf(lp[13653], -LLR_MAX), LLR_MAX);
                float s = ((W[8191] + msg[2][0]) + t5c1) - x;
                if (last) out_b[13653] = -s; else sh32[5461] = s;
            }
        }
        __syncthreads();

        // ---- E-t4 (msg[1] -> signed mags)  ||  stage t5 -> W ----
#pragma unroll
        for (int i = 0; i < 8; ++i) W[tid + THREADS * i] = msg[2][i];
        if (!last) {
#pragma unroll
            for (int i = 0; i < 8; ++i) {
                int e = tid + THREADS * i + 32768;
                int v = (int)(((unsigned)e * 43691u) >> 17);
                float m = sh32[v - 8192] - msg[1][i];
                msg[1][i] = signed_mag(m);
                __builtin_amdgcn_sched_barrier(0);
            }
        }
        __syncthreads();

        // ---- chunk t5: v in [13654,16384) ----
#pragma unroll
        for (int k = 0; k < 3; ++k) {
            int r = tid + THREADS * k;
            if (r < 2730) {
                int v = 13654 + r;
                float x = fminf(fmaxf(lp[v], -LLR_MAX), LLR_MAX);
                int j = 3 * r + 2;
                float s = ((W[j] + W[j + 1]) + W[j + 2]) - x;
                if (last) out_b[v] = -s; else sh32[5462 + r] = s;
            }
        }
        __syncthreads();

        if (!last) {
            // ---- E-t5 (msg[2] -> signed mags) ----
#pragma unroll
            for (int i = 0; i < 8; ++i) {
                int e = tid + THREADS * i + 40960;
                int v = (int)(((unsigned)e * 43691u) >> 17);
                float m = sh32[v - 8192] - msg[2][i];
                msg[2][i] = signed_mag(m);
                __builtin_amdgcn_sched_barrier(0);
            }
            // ---- pass 2: new messages from 6 signed mags per CN ----
#pragma unroll
            for (int i = 0; i < 8; ++i) {
                int c = tid + THREADS * i;
                float g0 = buf[c], g1 = buf[c + 8192], g2 = buf[c + 16384];
                float g3 = msg[0][i], g4 = msg[1][i], g5 = msg[2][i];
                float a0 = fabsf(g0), a1 = fabsf(g1), a2 = fabsf(g2);
                float a3 = fabsf(g3), a4 = fabsf(g4), a5 = fabsf(g5);
                // mag_sum in reference left-fold order
                float ms = ((((a0 + a1) + a2) + a3) + a4) + a5;
                unsigned all6 = (__float_as_uint(g0) ^ __float_as_uint(g1)
                               ^ __float_as_uint(g2) ^ __float_as_uint(g3)
                               ^ __float_as_uint(g4) ^ __float_as_uint(g5))
                              & 0x80000000u;
                {
                    float o = phi_f(ms - a0);
                    unsigned sg = all6 ^ (__float_as_uint(g0) & 0x80000000u);
                    buf[c] = __uint_as_float(__float_as_uint(o) ^ sg);
                    __builtin_amdgcn_sched_barrier(0);
                }
                {
                    float o = phi_f(ms - a1);
                    unsigned sg = all6 ^ (__float_as_uint(g1) & 0x80000000u);
                    buf[c + 8192] = __uint_as_float(__float_as_uint(o) ^ sg);
                    __builtin_amdgcn_sched_barrier(0);
                }
                {
                    float o = phi_f(ms - a2);
                    unsigned sg = all6 ^ (__float_as_uint(g2) & 0x80000000u);
                    buf[c + 16384] = __uint_as_float(__float_as_uint(o) ^ sg);
                    __builtin_amdgcn_sched_barrier(0);
                }
                {
                    float o = phi_f(ms - a3);
                    unsigned sg = all6 ^ (__float_as_uint(g3) & 0x80000000u);
                    msg[0][i] = __uint_as_float(__float_as_uint(o) ^ sg);
                    __builtin_amdgcn_sched_barrier(0);
                }
                {
                    float o = phi_f(ms - a4);
                    unsigned sg = all6 ^ (__float_as_uint(g4) & 0x80000000u);
                    msg[1][i] = __uint_as_float(__float_as_uint(o) ^ sg);
                    __builtin_amdgcn_sched_barrier(0);
                }
                {
                    float o = phi_f(ms - a5);
                    unsigned sg = all6 ^ (__float_as_uint(g5) & 0x80000000u);
                    msg[2][i] = __uint_as_float(__float_as_uint(o) ^ sg);
                    __builtin_amdgcn_sched_barrier(0);
                }
            }
        }
    }
}

extern "C" void kernel_launch(void* const* d_in, const int* in_sizes, int n_in,
                              void* d_out, int out_size, void* d_ws, size_t ws_size,
                              hipStream_t stream) {
    const float* llr_ch = (const float*)d_in[0];
    float* out = (float*)d_out;
    ldpc_bp_kernel<<<dim3(128), dim3(THREADS), 0, stream>>>(llr_ch, out);
}

// Round 12
// 329.415 us; speedup vs baseline: 1.8489x; 1.8489x over previous
//
#include <hip/hip_runtime.h>

// LDPC BP decoder, (3,6)-regular — multi-kernel, full-chip version.
// Edge e (vn order) = 3v+j; c = e mod 8192, t = e div 8192, so e = c + 8192t:
// ONE linear msg[b][e] layout is coalesced for both VN (e=3v+j) and CN
// (e=c+8192t) kernels. State in d_ws: msg 24MB + vtot 8MB = 32MB.
//
// r4-r11 lesson: the 160KB-LDS monolith used half the chip (128 WG/256 CU)
// at 4 waves/SIMD, and scratch-spill traffic proved uncorrelated with
// duration. This round: VN kernel (thread/VN) + CN kernel (thread/CN), no
// LDS, no barriers, ~30 live regs, 17 launches; all 256 CUs, 8 waves/SIMD.
// phi chain bit-identical to r9/r11 (lean f64 exp/log, absmax 0.25).

constexpr int NUM_VNS   = 16384;
constexpr int NUM_CNS   = 8192;
constexpr int NUM_EDGES = 49152;
constexpr int BATCH     = 128;
constexpr int NUM_ITER  = 8;
constexpr float LLR_MAX = 20.0f;
constexpr float PHI_MIN = 8.5e-8f;
constexpr float PHI_MAX = 16.635532f;

// exp(x) for x in [0, 16.64]; internal rel err ~2^-42.
__device__ __forceinline__ double lean_exp(double x) {
    double t = x * 1.4426950408889634;
    double k = __builtin_rint(t);
    double r = __builtin_fma(-k, 0.6931471805599453, x);
    r = __builtin_fma(-k, 2.3190468138462996e-17, r);
    double p = 1.0 / 3628800.0;                  // Taylor deg 10, |r|<=0.347
    p = __builtin_fma(p, r, 1.0 / 362880.0);
    p = __builtin_fma(p, r, 1.0 / 40320.0);
    p = __builtin_fma(p, r, 1.0 / 5040.0);
    p = __builtin_fma(p, r, 1.0 / 720.0);
    p = __builtin_fma(p, r, 1.0 / 120.0);
    p = __builtin_fma(p, r, 1.0 / 24.0);
    p = __builtin_fma(p, r, 1.0 / 6.0);
    p = __builtin_fma(p, r, 0.5);
    p = __builtin_fma(p, r, 1.0);
    p = __builtin_fma(p, r, 1.0);
    int ik = (int)k;                              // k in [0,24]
    double s = __hiloint2double((1023 + ik) << 20, 0);
    return p * s;
}

// log(v) for v in [2^-23, 2^25], v an exact f32 value; abs err ~2^-40.
__device__ __forceinline__ double lean_log(double v) {
    int hv = __double2hiint(v);
    int lv = __double2loint(v);
    int e  = (hv >> 20) - 1023;
    double m = __hiloint2double((hv & 0x000FFFFF) | 0x3FF00000, lv);
    if (m >= 1.4142135623730951) { m *= 0.5; e += 1; }   // m in [0.7071,1.4142)
    double t = m - 1.0;
    double d = t + 2.0;
    double r = (double)__builtin_amdgcn_rcpf((float)d);
    r = __builtin_fma(__builtin_fma(-d, r, 1.0), r, r);
    double u = t * r;
    double w = u * u;                             // w <= 0.0295
    double P = 2.0 / 13.0;                        // 2*artanh: deg 6 in w
    P = __builtin_fma(P, w, 2.0 / 11.0);
    P = __builtin_fma(P, w, 2.0 / 9.0);
    P = __builtin_fma(P, w, 2.0 / 7.0);
    P = __builtin_fma(P, w, 2.0 / 5.0);
    P = __builtin_fma(P, w, 2.0 / 3.0);
    P = __builtin_fma(P, w, 2.0);
    double lm = u * P;
    return __builtin_fma((double)e, 0.6931471805599453, lm);
}

// literal reference chain: clip; ex=f32(exp); a=ex+1, b=ex-1 in f32;
// la=f32(log a), lb=f32(log b); return la-lb.
__device__ __forceinline__ float phi_f(float xf) {
    xf = fminf(fmaxf(xf, PHI_MIN), PHI_MAX);
    float exf = (float)lean_exp((double)xf);
    float af = exf + 1.0f;
    float bf = exf - 1.0f;
    float la = (float)lean_log((double)af);
    float lb = (float)lean_log((double)bf);
    return la - lb;
}

// ---- VN kernel: one thread per (b, v). s = ((m0+m1)+m2) - clip(llr).
// FIRST: msgs are implicitly 0 (matches reference msg0 = 0; d_ws never read
// uninitialized). LAST: write -s to out instead of s to vtot.
template<int FIRST, int LAST>
__global__ __launch_bounds__(256)
void vn_kernel(const float* __restrict__ llr, const float* __restrict__ msg,
               float* __restrict__ outv)
{
    int gid = blockIdx.x * 256 + threadIdx.x;       // b*16384 + v
    int b = gid >> 14;
    int v = gid & 16383;
    float x = fminf(fmaxf(llr[gid], -LLR_MAX), LLR_MAX);
    float s;
    if (FIRST) {
        s = -x;
    } else {
        const float* mb = msg + (size_t)b * NUM_EDGES;
        int e = 3 * v;
        s = ((mb[e] + mb[e + 1]) + mb[e + 2]) - x;  // exact reference order
    }
    outv[gid] = LAST ? -s : s;
}

// ---- CN kernel: one thread per (b, c). All 12 phi in-thread; no LDS.
template<int FIRST>
__global__ __launch_bounds__(256)
void cn_kernel(float* __restrict__ msg, const float* __restrict__ vtot)
{
    int gid = blockIdx.x * 256 + threadIdx.x;       // b*8192 + c
    int b = gid >> 13;
    int c = gid & 8191;
    float* mb = msg + (size_t)b * NUM_EDGES;
    const float* vt = vtot + (size_t)b * NUM_VNS;

    float g[6];                                     // signed mags (sign in bit)
#pragma unroll
    for (int t = 0; t < 6; ++t) {
        int e = c + (t << 13);
        int v = (int)(((unsigned)e * 43691u) >> 17);  // e/3, e < 131072
        float m = FIRST ? vt[v] : (vt[v] - mb[e]);    // vn-extrinsic message
        unsigned neg = (m < 0.0f) ? 0x80000000u : 0u; // sign(0) -> +1
        float mg = phi_f(fabsf(m));
        g[t] = __uint_as_float(__float_as_uint(mg) | neg);
    }
    float a0 = fabsf(g[0]), a1 = fabsf(g[1]), a2 = fabsf(g[2]);
    float a3 = fabsf(g[3]), a4 = fabsf(g[4]), a5 = fabsf(g[5]);
    // mag_sum in reference left-fold (cn-edge) order
    float ms = ((((a0 + a1) + a2) + a3) + a4) + a5;
    unsigned all6 = (__float_as_uint(g[0]) ^ __float_as_uint(g[1])
                   ^ __float_as_uint(g[2]) ^ __float_as_uint(g[3])
                   ^ __float_as_uint(g[4]) ^ __float_as_uint(g[5]))
                  & 0x80000000u;
#pragma unroll
    for (int t = 0; t < 6; ++t) {
        int e = c + (t << 13);
        float o = phi_f(ms - fabsf(g[t]));
        unsigned sg = all6 ^ (__float_as_uint(g[t]) & 0x80000000u);
        mb[e] = __uint_as_float(__float_as_uint(o) ^ sg);
    }
}

extern "C" void kernel_launch(void* const* d_in, const int* in_sizes, int n_in,
                              void* d_out, int out_size, void* d_ws, size_t ws_size,
                              hipStream_t stream) {
    const float* llr = (const float*)d_in[0];
    float* out  = (float*)d_out;
    float* msg  = (float*)d_ws;                        // 128*49152 f32 = 24 MB
    float* vtot = msg + (size_t)BATCH * NUM_EDGES;     //  128*16384 f32 =  8 MB

    const int VNB = BATCH * NUM_VNS / 256;             // 8192 blocks
    const int CNB = BATCH * NUM_CNS / 256;             // 4096 blocks

    vn_kernel<1, 0><<<VNB, 256, 0, stream>>>(llr, msg, vtot);
    cn_kernel<1><<<CNB, 256, 0, stream>>>(msg, vtot);
    for (int it = 1; it < NUM_ITER; ++it) {
        vn_kernel<0, 0><<<VNB, 256, 0, stream>>>(llr, msg, vtot);
        cn_kernel<0><<<CNB, 256, 0, stream>>>(msg, vtot);
    }
    vn_kernel<0, 1><<<VNB, 256, 0, stream>>>(llr, msg, out);
}

// Round 13
// 271.723 us; speedup vs baseline: 2.2415x; 1.2123x over previous
//
#include <hip/hip_runtime.h>

// LDPC BP decoder, (3,6)-regular — fused full-chip version.
// Edge e (vn order) = 3v+j; c = e mod 8192, t = e div 8192, e = c + 8192t.
// One linear msg[b][e] layout is coalesced for both roles.
//
// r12 -> r13: fuse the VN pass into the CN kernel (each CN thread recomputes
// its 6 VN sums from the prev-iteration messages, bit-identical left-fold).
// Cross-thread read/write race resolved by double-buffering msg (2x24MB in
// d_ws). Host falls back to the proven r12 3-kernel path if ws_size < 48MB.
// phi chain bit-identical to r9-r12 (lean f64 exp/log, ~CR f32; absmax 0.25).

constexpr int NUM_VNS   = 16384;
constexpr int NUM_CNS   = 8192;
constexpr int NUM_EDGES = 49152;
constexpr int BATCH     = 128;
constexpr int NUM_ITER  = 8;
constexpr float LLR_MAX = 20.0f;
constexpr float PHI_MIN = 8.5e-8f;
constexpr float PHI_MAX = 16.635532f;

// exp(x) for x in [0, 16.64]; internal rel err ~2^-42.
__device__ __forceinline__ double lean_exp(double x) {
    double t = x * 1.4426950408889634;
    double k = __builtin_rint(t);
    double r = __builtin_fma(-k, 0.6931471805599453, x);
    r = __builtin_fma(-k, 2.3190468138462996e-17, r);
    double p = 1.0 / 3628800.0;                  // Taylor deg 10, |r|<=0.347
    p = __builtin_fma(p, r, 1.0 / 362880.0);
    p = __builtin_fma(p, r, 1.0 / 40320.0);
    p = __builtin_fma(p, r, 1.0 / 5040.0);
    p = __builtin_fma(p, r, 1.0 / 720.0);
    p = __builtin_fma(p, r, 1.0 / 120.0);
    p = __builtin_fma(p, r, 1.0 / 24.0);
    p = __builtin_fma(p, r, 1.0 / 6.0);
    p = __builtin_fma(p, r, 0.5);
    p = __builtin_fma(p, r, 1.0);
    p = __builtin_fma(p, r, 1.0);
    int ik = (int)k;                              // k in [0,24]
    double s = __hiloint2double((1023 + ik) << 20, 0);
    return p * s;
}

// log(v) for v in [2^-23, 2^25], v an exact f32 value; abs err ~2^-40.
__device__ __forceinline__ double lean_log(double v) {
    int hv = __double2hiint(v);
    int lv = __double2loint(v);
    int e  = (hv >> 20) - 1023;
    double m = __hiloint2double((hv & 0x000FFFFF) | 0x3FF00000, lv);
    if (m >= 1.4142135623730951) { m *= 0.5; e += 1; }   // m in [0.7071,1.4142)
    double t = m - 1.0;
    double d = t + 2.0;
    double r = (double)__builtin_amdgcn_rcpf((float)d);
    r = __builtin_fma(__builtin_fma(-d, r, 1.0), r, r);
    double u = t * r;
    double w = u * u;                             // w <= 0.0295
    double P = 2.0 / 13.0;                        // 2*artanh: deg 6 in w
    P = __builtin_fma(P, w, 2.0 / 11.0);
    P = __builtin_fma(P, w, 2.0 / 9.0);
    P = __builtin_fma(P, w, 2.0 / 7.0);
    P = __builtin_fma(P, w, 2.0 / 5.0);
    P = __builtin_fma(P, w, 2.0 / 3.0);
    P = __builtin_fma(P, w, 2.0);
    double lm = u * P;
    return __builtin_fma((double)e, 0.6931471805599453, lm);
}

// literal reference chain: clip; ex=f32(exp); a=ex+1, b=ex-1 in f32;
// la=f32(log a), lb=f32(log b); return la-lb.
__device__ __forceinline__ float phi_f(float xf) {
    xf = fminf(fmaxf(xf, PHI_MIN), PHI_MAX);
    float exf = (float)lean_exp((double)xf);
    float af = exf + 1.0f;
    float bf = exf - 1.0f;
    float la = (float)lean_log((double)af);
    float lb = (float)lean_log((double)bf);
    return la - lb;
}

// ---- fused CN kernel: one thread per (b, c). Recomputes vtot for its 6 VNs
// from msgIn (prev iteration), then the boxplus; writes msgOut. ----
template<int FIRST>
__global__ __launch_bounds__(256)
void cn_fused(const float* __restrict__ llr, const float* __restrict__ msgIn,
              float* __restrict__ msgOut)
{
    int gid = blockIdx.x * 256 + threadIdx.x;       // b*8192 + c
    int b = gid >> 13;
    int c = gid & 8191;
    const float* mi = msgIn + (size_t)b * NUM_EDGES;
    float* mo = msgOut + (size_t)b * NUM_EDGES;
    const float* lb = llr + (size_t)b * NUM_VNS;

    float g[6];                                     // signed mags (sign in bit)
#pragma unroll
    for (int t = 0; t < 6; ++t) {
        int e = c + (t << 13);
        int v = (int)(((unsigned)e * 43691u) >> 17);  // e/3, valid e < 98304
        float x = fminf(fmaxf(lb[v], -LLR_MAX), LLR_MAX);
        float m;
        if (FIRST) {
            m = -x;                                   // msgs are all zero
        } else {
            int e0 = 3 * v;
            float s = ((mi[e0] + mi[e0 + 1]) + mi[e0 + 2]) - x;  // exact order
            m = s - mi[e];                            // vn-extrinsic
        }
        unsigned neg = (m < 0.0f) ? 0x80000000u : 0u; // sign(0) -> +1
        float mg = phi_f(fabsf(m));
        g[t] = __uint_as_float(__float_as_uint(mg) | neg);
    }
    float a0 = fabsf(g[0]), a1 = fabsf(g[1]), a2 = fabsf(g[2]);
    float a3 = fabsf(g[3]), a4 = fabsf(g[4]), a5 = fabsf(g[5]);
    float ms = ((((a0 + a1) + a2) + a3) + a4) + a5;   // reference left-fold
    unsigned all6 = (__float_as_uint(g[0]) ^ __float_as_uint(g[1])
                   ^ __float_as_uint(g[2]) ^ __float_as_uint(g[3])
                   ^ __float_as_uint(g[4]) ^ __float_as_uint(g[5]))
                  & 0x80000000u;
#pragma unroll
    for (int t = 0; t < 6; ++t) {
        int e = c + (t << 13);
        float o = phi_f(ms - fabsf(g[t]));
        unsigned sg = all6 ^ (__float_as_uint(g[t]) & 0x80000000u);
        mo[e] = __uint_as_float(__float_as_uint(o) ^ sg);
    }
}

// ---- VN kernel (r12 fallback + final marginalize). ----
template<int FIRST, int LAST>
__global__ __launch_bounds__(256)
void vn_kernel(const float* __restrict__ llr, const float* __restrict__ msg,
               float* __restrict__ outv)
{
    int gid = blockIdx.x * 256 + threadIdx.x;       // b*16384 + v
    int b = gid >> 14;
    int v = gid & 16383;
    float x = fminf(fmaxf(llr[gid], -LLR_MAX), LLR_MAX);
    float s;
    if (FIRST) {
        s = -x;
    } else {
        const float* mb = msg + (size_t)b * NUM_EDGES;
        int e = 3 * v;
        s = ((mb[e] + mb[e + 1]) + mb[e + 2]) - x;  // exact reference order
    }
    outv[gid] = LAST ? -s : s;
}

// ---- CN kernel (r12 fallback, reads precomputed vtot). ----
template<int FIRST>
__global__ __launch_bounds__(256)
void cn_kernel(float* __restrict__ msg, const float* __restrict__ vtot)
{
    int gid = blockIdx.x * 256 + threadIdx.x;       // b*8192 + c
    int b = gid >> 13;
    int c = gid & 8191;
    float* mb = msg + (size_t)b * NUM_EDGES;
    const float* vt = vtot + (size_t)b * NUM_VNS;

    float g[6];
#pragma unroll
    for (int t = 0; t < 6; ++t) {
        int e = c + (t << 13);
        int v = (int)(((unsigned)e * 43691u) >> 17);
        float m = FIRST ? vt[v] : (vt[v] - mb[e]);
        unsigned neg = (m < 0.0f) ? 0x80000000u : 0u;
        float mg = phi_f(fabsf(m));
        g[t] = __uint_as_float(__float_as_uint(mg) | neg);
    }
    float a0 = fabsf(g[0]), a1 = fabsf(g[1]), a2 = fabsf(g[2]);
    float a3 = fabsf(g[3]), a4 = fabsf(g[4]), a5 = fabsf(g[5]);
    float ms = ((((a0 + a1) + a2) + a3) + a4) + a5;
    unsigned all6 = (__float_as_uint(g[0]) ^ __float_as_uint(g[1])
                   ^ __float_as_uint(g[2]) ^ __float_as_uint(g[3])
                   ^ __float_as_uint(g[4]) ^ __float_as_uint(g[5]))
                  & 0x80000000u;
#pragma unroll
    for (int t = 0; t < 6; ++t) {
        int e = c + (t << 13);
        float o = phi_f(ms - fabsf(g[t]));
        unsigned sg = all6 ^ (__float_as_uint(g[t]) & 0x80000000u);
        mb[e] = __uint_as_float(__float_as_uint(o) ^ sg);
    }
}

extern "C" void kernel_launch(void* const* d_in, const int* in_sizes, int n_in,
                              void* d_out, int out_size, void* d_ws, size_t ws_size,
                              hipStream_t stream) {
    const float* llr = (const float*)d_in[0];
    float* out = (float*)d_out;

    const int VNB = BATCH * NUM_VNS / 256;             // 8192 blocks
    const int CNB = BATCH * NUM_CNS / 256;             // 4096 blocks
    const size_t MSGSZ = (size_t)BATCH * NUM_EDGES;    // 6.29M floats = 24 MB

    if (ws_size >= 2 * MSGSZ * sizeof(float)) {
        // ---- fused path: 8 CN launches (double-buffered) + final VN ----
        float* buf0 = (float*)d_ws;
        float* buf1 = buf0 + MSGSZ;
        cn_fused<1><<<CNB, 256, 0, stream>>>(llr, buf0, buf0);     // writes buf0
        for (int it = 1; it < NUM_ITER; ++it) {
            float* in  = (it & 1) ? buf0 : buf1;
            float* dst = (it & 1) ? buf1 : buf0;
            cn_fused<0><<<CNB, 256, 0, stream>>>(llr, in, dst);
        }
        // NUM_ITER=8: last write was buf1 (it=7 -> dst=buf1)
        vn_kernel<0, 1><<<VNB, 256, 0, stream>>>(llr, buf1, out);
    } else {
        // ---- r12 fallback: 32 MB workspace ----
        float* msg  = (float*)d_ws;
        float* vtot = msg + MSGSZ;
        vn_kernel<1, 0><<<VNB, 256, 0, stream>>>(llr, msg, vtot);
        cn_kernel<1><<<CNB, 256, 0, stream>>>(msg, vtot);
        for (int it = 1; it < NUM_ITER; ++it) {
            vn_kernel<0, 0><<<VNB, 256, 0, stream>>>(llr, msg, vtot);
            cn_kernel<0><<<CNB, 256, 0, stream>>>(msg, vtot);
        }
        vn_kernel<0, 1><<<VNB, 256, 0, stream>>>(llr, msg, out);
    }
}